// Round 4
// baseline (11134.492 us; speedup 1.0000x reference)
//
#include <hip/hip_runtime.h>
#include <stdint.h>

#define B_ 4
#define T_ 4096
#define D_ 1024
#define H_ 16
#define HD_ 64
#define C_ 64
#define N_ 64
#define BT_ (B_*T_)

typedef unsigned short u16;

__device__ __forceinline__ float wave_sum(float v){
  #pragma unroll
  for(int off=32; off>0; off>>=1) v += __shfl_down(v, off);
  return __shfl(v, 0);
}

// ---------------------------------------------------------------------------
// K1: per-(b,t): invn = 1/||x_head||, gate/beta/decay projections
// ---------------------------------------------------------------------------
__global__ __launch_bounds__(256) void k_small(const float* __restrict__ x,
    const float* __restrict__ wg, const float* __restrict__ wb, const float* __restrict__ wa,
    const float* __restrict__ dtb, const float* __restrict__ alog,
    float* __restrict__ invn, float* __restrict__ gate, float* __restrict__ beta,
    float* __restrict__ dec){
  int row = blockIdx.x;            // b*T + t
  __shared__ float xs[D_];
  {
    int i0 = threadIdx.x*4;
    float4 u = *(const float4*)(x + (size_t)row*D_ + i0);
    xs[i0+0]=u.x; xs[i0+1]=u.y; xs[i0+2]=u.z; xs[i0+3]=u.w;
  }
  __syncthreads();
  int w = threadIdx.x>>6, l = threadIdx.x&63;
  #pragma unroll
  for(int i=0;i<4;++i){
    int h = w*4+i;
    float v = xs[h*64+l];
    float ss = wave_sum(v*v);
    float dg=0.f,db=0.f,da=0.f;
    #pragma unroll
    for(int k16=0;k16<16;++k16){
      int k = l + 64*k16;
      float xv = xs[k];
      dg += xv*wg[k*H_+h];
      db += xv*wb[k*H_+h];
      da += xv*wa[k*H_+h];
    }
    dg = wave_sum(dg); db = wave_sum(db); da = wave_sum(da);
    if(l==0){
      int o = row*H_+h;
      invn[o] = 1.f/fmaxf(sqrtf(ss),1e-12f);
      gate[o] = 1.f/(1.f+expf(-dg));
      beta[o] = 1.f/(1.f+expf(-db));
      float z = da + dtb[h];
      float sp = (z>20.f)? z : log1pf(expf(z));
      dec[o] = -expf(alog[h])*sp;
    }
  }
}

// ---------------------------------------------------------------------------
// K2: C(f32) = A(f32) @ B(f32), 128x128 tile, BK=8, 8x8/thread
// ---------------------------------------------------------------------------
#define BM 128
#define BN 128
#define BK 8
__global__ __launch_bounds__(256) void k_gemm_bb(const float* __restrict__ A,
    const float* __restrict__ Bw, float* __restrict__ Cc, int M, int Nn, int K){
  __shared__ float As[BK][BM];
  __shared__ float Bs[BK][BN];
  int tid = threadIdx.x;
  int tx = tid & 15, ty = tid >> 4;
  int m0 = blockIdx.y*BM, n0 = blockIdx.x*BN;
  int arow = tid>>1, ak = (tid&1)*4;
  int bk = tid>>5, bcol = (tid&31)*4;
  float acc[8][8] = {};
  for(int k0=0;k0<K;k0+=BK){
    float4 ua = *(const float4*)(A  + (size_t)(m0+arow)*K + k0+ak);
    float4 ub = *(const float4*)(Bw + (size_t)(k0+bk)*Nn + n0+bcol);
    __syncthreads();
    As[ak+0][arow]=ua.x; As[ak+1][arow]=ua.y;
    As[ak+2][arow]=ua.z; As[ak+3][arow]=ua.w;
    Bs[bk][bcol+0]=ub.x; Bs[bk][bcol+1]=ub.y;
    Bs[bk][bcol+2]=ub.z; Bs[bk][bcol+3]=ub.w;
    __syncthreads();
    #pragma unroll
    for(int kk=0;kk<BK;++kk){
      float a[8], b[8];
      *(float4*)&a[0] = *(const float4*)&As[kk][ty*8];
      *(float4*)&a[4] = *(const float4*)&As[kk][ty*8+4];
      *(float4*)&b[0] = *(const float4*)&Bs[kk][tx*8];
      *(float4*)&b[4] = *(const float4*)&Bs[kk][tx*8+4];
      #pragma unroll
      for(int i=0;i<8;++i)
        #pragma unroll
        for(int j=0;j<8;++j) acc[i][j] += a[i]*b[j];
    }
  }
  for(int i=0;i<8;++i){
    float4 v0 = {acc[i][0],acc[i][1],acc[i][2],acc[i][3]};
    float4 v1 = {acc[i][4],acc[i][5],acc[i][6],acc[i][7]};
    *(float4*)(Cc + (size_t)(m0+ty*8+i)*Nn + n0+tx*8)   = v0;
    *(float4*)(Cc + (size_t)(m0+ty*8+i)*Nn + n0+tx*8+4) = v1;
  }
}

// ---------------------------------------------------------------------------
// K6: Out(f32) = resid(f32) + A(f32) @ B(f32)
// ---------------------------------------------------------------------------
__global__ __launch_bounds__(256) void k_gemm_out(const float* __restrict__ A,
    const float* __restrict__ Bw, const float* __restrict__ resid, float* __restrict__ Outp,
    int M, int Nn, int K){
  __shared__ float As[BK][BM];
  __shared__ float Bs[BK][BN];
  int tid = threadIdx.x;
  int tx = tid & 15, ty = tid >> 4;
  int m0 = blockIdx.y*BM, n0 = blockIdx.x*BN;
  int arow = tid>>1, ak = (tid&1)*4;
  int bk = tid>>5, bcol = (tid&31)*4;
  float acc[8][8] = {};
  for(int k0=0;k0<K;k0+=BK){
    float4 fa = *(const float4*)(A + (size_t)(m0+arow)*K + k0+ak);
    float4 ub = *(const float4*)(Bw + (size_t)(k0+bk)*Nn + n0+bcol);
    __syncthreads();
    As[ak+0][arow]=fa.x; As[ak+1][arow]=fa.y; As[ak+2][arow]=fa.z; As[ak+3][arow]=fa.w;
    Bs[bk][bcol+0]=ub.x; Bs[bk][bcol+1]=ub.y;
    Bs[bk][bcol+2]=ub.z; Bs[bk][bcol+3]=ub.w;
    __syncthreads();
    #pragma unroll
    for(int kk=0;kk<BK;++kk){
      float a[8], b[8];
      *(float4*)&a[0] = *(const float4*)&As[kk][ty*8];
      *(float4*)&a[4] = *(const float4*)&As[kk][ty*8+4];
      *(float4*)&b[0] = *(const float4*)&Bs[kk][tx*8];
      *(float4*)&b[4] = *(const float4*)&Bs[kk][tx*8+4];
      #pragma unroll
      for(int i=0;i<8;++i)
        #pragma unroll
        for(int j=0;j<8;++j) acc[i][j] += a[i]*b[j];
    }
  }
  for(int i=0;i<8;++i){
    size_t ro = (size_t)(m0+ty*8+i)*Nn + n0+tx*8;
    float4 r0 = *(const float4*)(resid + ro);
    float4 r1 = *(const float4*)(resid + ro + 4);
    float4 s0, s1;
    s0.x=acc[i][0]+r0.x; s0.y=acc[i][1]+r0.y;
    s0.z=acc[i][2]+r0.z; s0.w=acc[i][3]+r0.w;
    s1.x=acc[i][4]+r1.x; s1.y=acc[i][5]+r1.y;
    s1.z=acc[i][6]+r1.z; s1.w=acc[i][7]+r1.w;
    *(float4*)(Outp + ro)     = s0;
    *(float4*)(Outp + ro + 4) = s1;
  }
}

// ---------------------------------------------------------------------------
// K3: per-chunk: cum, KK, forward substitution -> v_corr (in-place in vbuf),
//     wk_cd -> wkop
// ---------------------------------------------------------------------------
__global__ __launch_bounds__(256) void k_chunk(const float* __restrict__ x,
    const float* __restrict__ invn, const float* __restrict__ beta_g,
    const float* __restrict__ dec_g, float* __restrict__ cum_g,
    float* __restrict__ vbuf, float* __restrict__ wkop){
  int bid = blockIdx.x;                  // b*H*N + h*N + n
  int n = bid & 63; int h = (bid>>6) & 15; int b = bid>>10;
  int t0 = n*C_;
  __shared__ float sm[12608];
  float* WK = sm;            // 64*65 (padded), aliased by XV later
  float* KK = sm+4160;       // 64*64
  float* XW = sm+8256;       // 64*64
  float* BS = sm+12352;      // 64
  float* CU = sm+12416;      // 64
  float* DE = sm+12480;      // 64
  float* GS = sm+12544;      // 64
  float* XV = WK;            // 4096 over WK region (stride 64)
  int tid = threadIdx.x, w = tid>>6, l = tid&63;
  // A: stage shifted normalized keys + beta + decay
  #pragma unroll
  for(int it=0; it<16; ++it){
    int idx = tid + 256*it; int c = idx>>6, dd = idx&63;
    int tw = t0+c-1;
    float wv = 0.f;
    if(tw>=0){
      size_t rr = (size_t)(b*T_+tw);
      wv = x[rr*D_ + h*64 + dd] * invn[rr*H_ + h];
    }
    WK[c*65+dd] = wv;
  }
  if(tid<64){
    size_t rr = (size_t)(b*T_+t0+tid);
    BS[tid] = beta_g[rr*H_+h];
    GS[tid] = dec_g[rr*H_+h];
  }
  __syncthreads();
  // B: inclusive cumsum of decay (wave 0)
  if(w==0){
    float xg = GS[l];
    #pragma unroll
    for(int off=1; off<64; off<<=1){
      float y = __shfl_up(xg, off);
      if(l>=off) xg += y;
    }
    CU[l]=xg; DE[l]=expf(xg);
    cum_g[(size_t)bid*64 + l] = xg;
  }
  __syncthreads();
  // C: KK[i][j] = beta_i * (wk_i . wk_j) * L[i][j], strict lower
  float wkj[64];
  #pragma unroll
  for(int dd=0; dd<64; ++dd) wkj[dd] = WK[l*65+dd];
  #pragma unroll 1
  for(int it=0; it<16; ++it){
    int i = w + 4*it;
    float aw=0.f;
    #pragma unroll
    for(int dd=0; dd<64; ++dd) aw += WK[i*65+dd]*wkj[dd];
    KK[i*64+l] = (l<i) ? (BS[i]*aw*expf(CU[i]-CU[l])) : 0.f;
  }
  __syncthreads();
  // D: capture rhs into regs, then write XV (over WK), XW
  float rv[16], rw[16];
  #pragma unroll
  for(int it=0; it<16; ++it){
    int i = w + 4*it;
    rw[it] = WK[i*65+l]*BS[i]*DE[i];
    rv[it] = vbuf[(size_t)(b*T_+t0+i)*D_ + h*64 + l]*BS[i];
  }
  __syncthreads();
  #pragma unroll
  for(int it=0; it<16; ++it){
    int i = w + 4*it;
    XV[i*64+l] = rv[it];
    XW[i*64+l] = rw[it];
  }
  __syncthreads();
  // E: forward substitution (I + strict_lower(KK)) X = rhs (waves 0,1)
  if(w<2){
    float* Xc = (w==0) ? XV : XW;
    for(int i=1;i<64;++i){
      float acc = Xc[i*64+l];
      for(int k=0;k<i;++k) acc -= KK[i*64+k]*Xc[k*64+l];
      Xc[i*64+l] = acc;
    }
  }
  __syncthreads();
  // F: write v_corr (in place), wk_cd
  #pragma unroll
  for(int it=0; it<16; ++it){
    int i = w + 4*it;
    vbuf[(size_t)(b*T_+t0+i)*D_ + h*64 + l] = XV[i*64+l];
    wkop[(size_t)bid*4096 + i*64 + l]       = XW[i*64+l];
  }
}

// ---------------------------------------------------------------------------
// K4: sequential scan per (b,h): v_new (in-place), opart = (rk*dexp)@S_pre
//     (overwrites wkop chunk), S update + norm clip
// ---------------------------------------------------------------------------
__global__ __launch_bounds__(256) void k_scan(const float* __restrict__ x,
    const float* __restrict__ invn, const float* __restrict__ cum_g,
    float* __restrict__ vbuf, float* __restrict__ wkop){
  int bh = blockIdx.x;  // b*H + h
  int b = bh>>4, h = bh&15;
  __shared__ float sm[12356];
  float* S   = sm;          // 64x64 state
  float* VN  = sm+4096;     // v_new chunk
  float* AUX = sm+8192;     // wkcd chunk, then rk chunk
  float* CUc = sm+12288;    // 64
  float* P   = sm+12352;    // 4
  int tid = threadIdx.x, w = tid>>6, l = tid&63;
  #pragma unroll
  for(int it=0;it<16;++it) S[tid+256*it]=0.f;
  __syncthreads();
  for(int n=0;n<N_;++n){
    int t0 = n*C_;
    size_t base = ((size_t)bh*N_ + n)*4096;
    size_t cb   = ((size_t)bh*N_ + n)*64;
    // stage wkcd chunk + cum
    if(tid<64) CUc[tid] = cum_g[cb+tid];
    #pragma unroll 1
    for(int it=0;it<16;++it){ int idx=tid+256*it; AUX[idx]=wkop[base+idx]; }
    __syncthreads();
    float last = CUc[63], elast = expf(last);
    float s_col[64];
    #pragma unroll
    for(int k=0;k<64;++k) s_col[k] = S[k*64+l];
    // v_new = v_corr - wkcd @ S_pre (in place)
    #pragma unroll 1
    for(int it=0;it<16;++it){
      int c = w+4*it;
      size_t vix = (size_t)(b*T_+t0+c)*D_ + h*64 + l;
      float acc = vbuf[vix];
      #pragma unroll
      for(int d4=0; d4<16; ++d4){
        float4 a4 = *(const float4*)&AUX[c*64 + 4*d4];
        acc -= a4.x*s_col[4*d4] + a4.y*s_col[4*d4+1] + a4.z*s_col[4*d4+2] + a4.w*s_col[4*d4+3];
      }
      VN[c*64+l] = acc;
      vbuf[vix]  = acc;
    }
    __syncthreads();
    // restage AUX = rk chunk (unshifted)
    #pragma unroll 1
    for(int it=0;it<16;++it){
      int idx = tid+256*it; int c = idx>>6, dd = idx&63;
      size_t rr = (size_t)(b*T_+t0+c);
      AUX[c*64+dd] = x[rr*D_ + h*64 + dd] * invn[rr*H_ + h];
    }
    __syncthreads();
    // opart = dexp_c * (rk_c . S_pre[:,l]) -> overwrite wkop chunk
    #pragma unroll 1
    for(int it=0;it<16;++it){
      int c = w+4*it;
      float acc = 0.f;
      #pragma unroll
      for(int d4=0; d4<16; ++d4){
        float4 a4 = *(const float4*)&AUX[c*64 + 4*d4];
        acc += a4.x*s_col[4*d4] + a4.y*s_col[4*d4+1] + a4.z*s_col[4*d4+2] + a4.w*s_col[4*d4+3];
      }
      wkop[base + c*64 + l] = expf(CUc[c])*acc;
    }
    // S update: S = elast*S + sum_c wk[c][r]*dw[c]*VN[c][l]
    // wk[c] = rk[t0+c-1] = AUX[c-1] for c>=1; wk[0] from global (or 0 at t0==0)
    float vns[64];
    #pragma unroll
    for(int c=0;c<64;++c) vns[c] = VN[c*64+l]*expf(last - CUc[c]);
    float sn[16];
    #pragma unroll
    for(int it=0;it<16;++it){
      int r = w+4*it;
      float w0r = 0.f;
      if(t0>0){
        size_t r2 = (size_t)(b*T_+t0-1);
        w0r = x[r2*D_ + h*64 + r] * invn[r2*H_ + h];
      }
      float acc = elast*S[r*64+l] + w0r*vns[0];
      #pragma unroll
      for(int c=1;c<64;++c) acc += AUX[(c-1)*64 + r]*vns[c];
      sn[it] = acc;
    }
    // Frobenius norm clip
    float p = 0.f;
    #pragma unroll
    for(int it=0;it<16;++it) p += sn[it]*sn[it];
    p = wave_sum(p);
    if(l==0) P[w] = p;
    __syncthreads();
    float nrm = sqrtf(P[0]+P[1]+P[2]+P[3]);
    float scale = fminf(nrm,100.f)/fmaxf(nrm,1e-6f);
    #pragma unroll
    for(int it=0;it<16;++it){ int r=w+4*it; S[r*64+l] = sn[it]*scale; }
    __syncthreads();
  }
}

// ---------------------------------------------------------------------------
// K5: o = gate*(opart + intra @ v_new); intra recomputed from rk/wk; o in-place
// ---------------------------------------------------------------------------
__global__ __launch_bounds__(256) void k_o(const float* __restrict__ x,
    const float* __restrict__ invn, const float* __restrict__ cum_g,
    const float* __restrict__ wkop, const float* __restrict__ gate_g,
    float* __restrict__ vbuf){
  int bid = blockIdx.x; int n = bid&63, h=(bid>>6)&15, b=bid>>10;
  int t0 = n*C_;
  __shared__ float sm[8256];
  float* RK = sm;        // 64x64 rk chunk, later INT (intra)
  float* VN = sm+4096;   // 64x64 v_new chunk
  float* CU = sm+8192;   // 64
  float* INT = RK;
  int tid=threadIdx.x, w=tid>>6, l=tid&63;
  if(tid<64) CU[tid] = cum_g[(size_t)bid*64 + tid];
  #pragma unroll 1
  for(int it=0;it<16;++it){
    int idx = tid+256*it; int c=idx>>6, dd=idx&63;
    size_t rr = (size_t)(b*T_+t0+c);
    RK[c*64+dd] = x[rr*D_ + h*64 + dd] * invn[rr*H_ + h];
    VN[idx]     = vbuf[rr*D_ + h*64 + dd];
  }
  __syncthreads();
  // wk column j=l into regs (wk[l] = rk[t0+l-1])
  float wkj[64];
  {
    int tw = t0+l-1;
    if(tw>=0){
      size_t r2 = (size_t)(b*T_+tw);
      float iv = invn[r2*H_ + h];
      #pragma unroll
      for(int d4=0; d4<16; ++d4){
        float4 u = *(const float4*)(x + r2*D_ + h*64 + 4*d4);
        wkj[4*d4+0]=u.x*iv; wkj[4*d4+1]=u.y*iv;
        wkj[4*d4+2]=u.z*iv; wkj[4*d4+3]=u.w*iv;
      }
    } else {
      #pragma unroll
      for(int dd=0;dd<64;++dd) wkj[dd]=0.f;
    }
  }
  // intra[i][l] = (rk_i . wk_l) * L[i][l]; write over RK (lockstep-safe per row)
  #pragma unroll 1
  for(int it=0;it<16;++it){
    int i = w + 4*it;
    float ar = 0.f;
    #pragma unroll
    for(int d4=0; d4<16; ++d4){
      float4 r4 = *(const float4*)&RK[i*64 + 4*d4];
      ar += r4.x*wkj[4*d4] + r4.y*wkj[4*d4+1] + r4.z*wkj[4*d4+2] + r4.w*wkj[4*d4+3];
    }
    float val = (l<=i) ? (ar*expf(CU[i]-CU[l])) : 0.f;
    INT[i*64+l] = val;   // all lanes' reads of row i complete before this (lockstep)
  }
  __syncthreads();
  float vn_col[64];
  #pragma unroll
  for(int k=0;k<64;++k) vn_col[k] = VN[k*64+l];
  #pragma unroll 1
  for(int it=0;it<16;++it){
    int c = w+4*it;
    float acc = 0.f;
    #pragma unroll
    for(int d4=0; d4<16; ++d4){
      float4 i4 = *(const float4*)&INT[c*64 + 4*d4];
      acc += i4.x*vn_col[4*d4] + i4.y*vn_col[4*d4+1] + i4.z*vn_col[4*d4+2] + i4.w*vn_col[4*d4+3];
    }
    size_t rr = (size_t)(b*T_+t0+c);
    float g  = gate_g[rr*H_ + h];
    float op = wkop[(size_t)bid*4096 + c*64 + l];
    vbuf[rr*D_ + h*64 + l] = (op + acc)*g;
  }
}

// ---------------------------------------------------------------------------
extern "C" void kernel_launch(void* const* d_in, const int* in_sizes, int n_in,
                              void* d_out, int out_size, void* d_ws, size_t ws_size,
                              hipStream_t stream) {
  const float* x       = (const float*)d_in[0];
  const float* w_write = (const float*)d_in[1];
  const float* w_gate  = (const float*)d_in[2];
  const float* w_out   = (const float*)d_in[3];
  const float* w_beta  = (const float*)d_in[4];
  const float* w_alpha = (const float*)d_in[5];
  const float* dt_bias = (const float*)d_in[6];
  const float* A_log   = (const float*)d_in[7];
  float* outp = (float*)d_out;

  const size_t big   = (size_t)BT_*D_;   // 16,777,216 floats
  const size_t small = (size_t)BT_*H_;   //    262,144 floats
  const size_t need  = (2*big + 5*small)*sizeof(float);   // ~139.5 MB
  if(ws_size < need) return;   // diagnostic: wrong-answer instead of fault

  float* ws   = (float*)d_ws;
  float* vbuf = ws;              // v -> v_corr -> v_new -> o
  float* wkop = vbuf + big;      // wk_cd -> opart
  float* invn = wkop + big;
  float* gate = invn + small;
  float* beta = gate + small;
  float* dec  = beta + small;
  float* cum  = dec  + small;

  k_small<<<dim3(BT_), dim3(256), 0, stream>>>(x, w_gate, w_beta, w_alpha,
      dt_bias, A_log, invn, gate, beta, dec);
  k_gemm_bb<<<dim3(D_/BN, BT_/BM), dim3(256), 0, stream>>>(x, w_write, vbuf,
      BT_, D_, D_);
  k_chunk<<<dim3(B_*H_*N_), dim3(256), 0, stream>>>(x, invn, beta, dec,
      cum, vbuf, wkop);
  k_scan<<<dim3(B_*H_), dim3(256), 0, stream>>>(x, invn, cum, vbuf, wkop);
  k_o<<<dim3(B_*H_*N_), dim3(256), 0, stream>>>(x, invn, cum, wkop, gate, vbuf);
  k_gemm_out<<<dim3(D_/BN, BT_/BM), dim3(256), 0, stream>>>(vbuf, w_out, x,
      outp, BT_, D_, D_);
}

// Round 5
// 4544.280 us; speedup vs baseline: 2.4502x; 2.4502x over previous
//
#include <hip/hip_runtime.h>
#include <stdint.h>

#define B_ 4
#define T_ 4096
#define D_ 1024
#define H_ 16
#define HD_ 64
#define C_ 64
#define N_ 64
#define BT_ (B_*T_)

typedef unsigned short u16;

__device__ __forceinline__ float wave_sum(float v){
  #pragma unroll
  for(int off=32; off>0; off>>=1) v += __shfl_down(v, off);
  return __shfl(v, 0);
}

// ---------------------------------------------------------------------------
// K1: per-(b,t): invn = 1/||x_head||, gate/beta/decay projections
// ---------------------------------------------------------------------------
__global__ __launch_bounds__(256) void k_small(const float* __restrict__ x,
    const float* __restrict__ wg, const float* __restrict__ wb, const float* __restrict__ wa,
    const float* __restrict__ dtb, const float* __restrict__ alog,
    float* __restrict__ invn, float* __restrict__ gate, float* __restrict__ beta,
    float* __restrict__ dec){
  int row = blockIdx.x;            // b*T + t
  __shared__ float xs[D_];
  {
    int i0 = threadIdx.x*4;
    float4 u = *(const float4*)(x + (size_t)row*D_ + i0);
    xs[i0+0]=u.x; xs[i0+1]=u.y; xs[i0+2]=u.z; xs[i0+3]=u.w;
  }
  __syncthreads();
  int w = threadIdx.x>>6, l = threadIdx.x&63;
  #pragma unroll
  for(int i=0;i<4;++i){
    int h = w*4+i;
    float v = xs[h*64+l];
    float ss = wave_sum(v*v);
    float dg=0.f,db=0.f,da=0.f;
    #pragma unroll
    for(int k16=0;k16<16;++k16){
      int k = l + 64*k16;
      float xv = xs[k];
      dg += xv*wg[k*H_+h];
      db += xv*wb[k*H_+h];
      da += xv*wa[k*H_+h];
    }
    dg = wave_sum(dg); db = wave_sum(db); da = wave_sum(da);
    if(l==0){
      int o = row*H_+h;
      invn[o] = 1.f/fmaxf(sqrtf(ss),1e-12f);
      gate[o] = 1.f/(1.f+expf(-dg));
      beta[o] = 1.f/(1.f+expf(-db));
      float z = da + dtb[h];
      float sp = (z>20.f)? z : log1pf(expf(z));
      dec[o] = -expf(alog[h])*sp;
    }
  }
}

// ---------------------------------------------------------------------------
// K2: C(f32) = A(f32) @ B(f32), 128x128 tile, BK=8, 8x8/thread
// ---------------------------------------------------------------------------
#define BM 128
#define BN 128
#define BK 8
__global__ __launch_bounds__(256) void k_gemm_bb(const float* __restrict__ A,
    const float* __restrict__ Bw, float* __restrict__ Cc, int M, int Nn, int K){
  __shared__ float As[BK][BM];
  __shared__ float Bs[BK][BN];
  int tid = threadIdx.x;
  int tx = tid & 15, ty = tid >> 4;
  int m0 = blockIdx.y*BM, n0 = blockIdx.x*BN;
  int arow = tid>>1, ak = (tid&1)*4;
  int bk = tid>>5, bcol = (tid&31)*4;
  float acc[8][8] = {};
  for(int k0=0;k0<K;k0+=BK){
    float4 ua = *(const float4*)(A  + (size_t)(m0+arow)*K + k0+ak);
    float4 ub = *(const float4*)(Bw + (size_t)(k0+bk)*Nn + n0+bcol);
    __syncthreads();
    As[ak+0][arow]=ua.x; As[ak+1][arow]=ua.y;
    As[ak+2][arow]=ua.z; As[ak+3][arow]=ua.w;
    Bs[bk][bcol+0]=ub.x; Bs[bk][bcol+1]=ub.y;
    Bs[bk][bcol+2]=ub.z; Bs[bk][bcol+3]=ub.w;
    __syncthreads();
    #pragma unroll
    for(int kk=0;kk<BK;++kk){
      float a[8], b[8];
      *(float4*)&a[0] = *(const float4*)&As[kk][ty*8];
      *(float4*)&a[4] = *(const float4*)&As[kk][ty*8+4];
      *(float4*)&b[0] = *(const float4*)&Bs[kk][tx*8];
      *(float4*)&b[4] = *(const float4*)&Bs[kk][tx*8+4];
      #pragma unroll
      for(int i=0;i<8;++i)
        #pragma unroll
        for(int j=0;j<8;++j) acc[i][j] += a[i]*b[j];
    }
  }
  for(int i=0;i<8;++i){
    float4 v0 = {acc[i][0],acc[i][1],acc[i][2],acc[i][3]};
    float4 v1 = {acc[i][4],acc[i][5],acc[i][6],acc[i][7]};
    *(float4*)(Cc + (size_t)(m0+ty*8+i)*Nn + n0+tx*8)   = v0;
    *(float4*)(Cc + (size_t)(m0+ty*8+i)*Nn + n0+tx*8+4) = v1;
  }
}

// ---------------------------------------------------------------------------
// K6: Out(f32) = resid(f32) + A(f32) @ B(f32)
// ---------------------------------------------------------------------------
__global__ __launch_bounds__(256) void k_gemm_out(const float* __restrict__ A,
    const float* __restrict__ Bw, const float* __restrict__ resid, float* __restrict__ Outp,
    int M, int Nn, int K){
  __shared__ float As[BK][BM];
  __shared__ float Bs[BK][BN];
  int tid = threadIdx.x;
  int tx = tid & 15, ty = tid >> 4;
  int m0 = blockIdx.y*BM, n0 = blockIdx.x*BN;
  int arow = tid>>1, ak = (tid&1)*4;
  int bk = tid>>5, bcol = (tid&31)*4;
  float acc[8][8] = {};
  for(int k0=0;k0<K;k0+=BK){
    float4 fa = *(const float4*)(A + (size_t)(m0+arow)*K + k0+ak);
    float4 ub = *(const float4*)(Bw + (size_t)(k0+bk)*Nn + n0+bcol);
    __syncthreads();
    As[ak+0][arow]=fa.x; As[ak+1][arow]=fa.y; As[ak+2][arow]=fa.z; As[ak+3][arow]=fa.w;
    Bs[bk][bcol+0]=ub.x; Bs[bk][bcol+1]=ub.y;
    Bs[bk][bcol+2]=ub.z; Bs[bk][bcol+3]=ub.w;
    __syncthreads();
    #pragma unroll
    for(int kk=0;kk<BK;++kk){
      float a[8], b[8];
      *(float4*)&a[0] = *(const float4*)&As[kk][ty*8];
      *(float4*)&a[4] = *(const float4*)&As[kk][ty*8+4];
      *(float4*)&b[0] = *(const float4*)&Bs[kk][tx*8];
      *(float4*)&b[4] = *(const float4*)&Bs[kk][tx*8+4];
      #pragma unroll
      for(int i=0;i<8;++i)
        #pragma unroll
        for(int j=0;j<8;++j) acc[i][j] += a[i]*b[j];
    }
  }
  for(int i=0;i<8;++i){
    size_t ro = (size_t)(m0+ty*8+i)*Nn + n0+tx*8;
    float4 r0 = *(const float4*)(resid + ro);
    float4 r1 = *(const float4*)(resid + ro + 4);
    float4 s0, s1;
    s0.x=acc[i][0]+r0.x; s0.y=acc[i][1]+r0.y;
    s0.z=acc[i][2]+r0.z; s0.w=acc[i][3]+r0.w;
    s1.x=acc[i][4]+r1.x; s1.y=acc[i][5]+r1.y;
    s1.z=acc[i][6]+r1.z; s1.w=acc[i][7]+r1.w;
    *(float4*)(Outp + ro)     = s0;
    *(float4*)(Outp + ro + 4) = s1;
  }
}

// ---------------------------------------------------------------------------
// K3: per-chunk: cum, KK, forward substitution -> v_corr (in-place in vbuf),
//     wk_cd -> wkop
// ---------------------------------------------------------------------------
__global__ __launch_bounds__(256) void k_chunk(const float* __restrict__ x,
    const float* __restrict__ invn, const float* __restrict__ beta_g,
    const float* __restrict__ dec_g, float* __restrict__ cum_g,
    float* __restrict__ vbuf, float* __restrict__ wkop){
  int bid = blockIdx.x;                  // b*H*N + h*N + n
  int n = bid & 63; int h = (bid>>6) & 15; int b = bid>>10;
  int t0 = n*C_;
  __shared__ float sm[12608];
  float* WK = sm;            // 64*65 (padded), aliased by XV later
  float* KK = sm+4160;       // 64*64
  float* XW = sm+8256;       // 64*64
  float* BS = sm+12352;      // 64
  float* CU = sm+12416;      // 64
  float* DE = sm+12480;      // 64
  float* GS = sm+12544;      // 64
  float* XV = WK;            // 4096 over WK region (stride 64)
  int tid = threadIdx.x, w = tid>>6, l = tid&63;
  // A: stage shifted normalized keys + beta + decay
  #pragma unroll
  for(int it=0; it<16; ++it){
    int idx = tid + 256*it; int c = idx>>6, dd = idx&63;
    int tw = t0+c-1;
    float wv = 0.f;
    if(tw>=0){
      size_t rr = (size_t)(b*T_+tw);
      wv = x[rr*D_ + h*64 + dd] * invn[rr*H_ + h];
    }
    WK[c*65+dd] = wv;
  }
  if(tid<64){
    size_t rr = (size_t)(b*T_+t0+tid);
    BS[tid] = beta_g[rr*H_+h];
    GS[tid] = dec_g[rr*H_+h];
  }
  __syncthreads();
  // B: inclusive cumsum of decay (wave 0)
  if(w==0){
    float xg = GS[l];
    #pragma unroll
    for(int off=1; off<64; off<<=1){
      float y = __shfl_up(xg, off);
      if(l>=off) xg += y;
    }
    CU[l]=xg; DE[l]=expf(xg);
    cum_g[(size_t)bid*64 + l] = xg;
  }
  __syncthreads();
  // C: KK[i][j] = beta_i * (wk_i . wk_j) * L[i][j], strict lower
  float wkj[64];
  #pragma unroll
  for(int dd=0; dd<64; ++dd) wkj[dd] = WK[l*65+dd];
  #pragma unroll 1
  for(int it=0; it<16; ++it){
    int i = w + 4*it;
    float aw=0.f;
    #pragma unroll
    for(int dd=0; dd<64; ++dd) aw += WK[i*65+dd]*wkj[dd];
    KK[i*64+l] = (l<i) ? (BS[i]*aw*expf(CU[i]-CU[l])) : 0.f;
  }
  __syncthreads();
  // D: capture rhs into regs, then write XV (over WK), XW
  float rv[16], rw[16];
  #pragma unroll
  for(int it=0; it<16; ++it){
    int i = w + 4*it;
    rw[it] = WK[i*65+l]*BS[i]*DE[i];
    rv[it] = vbuf[(size_t)(b*T_+t0+i)*D_ + h*64 + l]*BS[i];
  }
  __syncthreads();
  #pragma unroll
  for(int it=0; it<16; ++it){
    int i = w + 4*it;
    XV[i*64+l] = rv[it];
    XW[i*64+l] = rw[it];
  }
  __syncthreads();
  // E: forward substitution (I + strict_lower(KK)) X = rhs (waves 0,1)
  if(w<2){
    float* Xc = (w==0) ? XV : XW;
    for(int i=1;i<64;++i){
      float acc = Xc[i*64+l];
      for(int k=0;k<i;++k) acc -= KK[i*64+k]*Xc[k*64+l];
      Xc[i*64+l] = acc;
    }
  }
  __syncthreads();
  // F: write v_corr (in place), wk_cd
  #pragma unroll
  for(int it=0; it<16; ++it){
    int i = w + 4*it;
    vbuf[(size_t)(b*T_+t0+i)*D_ + h*64 + l] = XV[i*64+l];
    wkop[(size_t)bid*4096 + i*64 + l]       = XW[i*64+l];
  }
}

// ---------------------------------------------------------------------------
// K4 v2: sequential scan per (b,h), software-pipelined global prefetch.
//   per chunk: v_new (in-place vbuf), opart (overwrites wkop), S update+clip.
// ---------------------------------------------------------------------------
__global__ __launch_bounds__(256) void k_scan(const float* __restrict__ x,
    const float* __restrict__ invn_g, const float* __restrict__ cum_g,
    float* __restrict__ vbuf, float* __restrict__ wkop){
  int bh = blockIdx.x;  // b*H + h
  int b = bh>>4, h = bh&15;
  __shared__ float sm[12612];
  float* S   = sm;          // 64x64 state
  float* WCD = sm+4096;     // wkcd chunk; later VNS (= v_new * DW)
  float* RK  = sm+8192;     // rk chunk (pre-scaled by invn)
  float* INV = sm+12288;    // 64
  float* CU  = sm+12352;    // 64
  float* DW  = sm+12416;    // 64: exp(last-cum)
  float* DEc = sm+12480;    // 64: exp(cum)
  float* PREV= sm+12544;    // 64: prev chunk's last rk row (scaled)
  float* P   = sm+12608;    // 4
  int tid = threadIdx.x, w = tid>>6, l = tid&63;

  #pragma unroll
  for(int it=0;it<16;++it) S[tid+256*it]=0.f;
  if(tid<64) PREV[tid]=0.f;

  // prologue: prefetch chunk 0 into regs
  float4 pW[4], pR[4];
  float pV[16], pI=0.f, pC=0.f;
  {
    size_t base0 = (size_t)bh*N_*4096;
    #pragma unroll
    for(int j=0;j<4;++j){
      int idx4 = tid + 256*j;
      pW[j] = *(const float4*)(wkop + base0 + (size_t)idx4*4);
      int c = idx4>>4, c4 = (idx4&15)*4;
      pR[j] = *(const float4*)(x + (size_t)(b*T_+c)*D_ + h*64 + c4);
    }
    #pragma unroll
    for(int it=0;it<16;++it){
      int c = 16*w+it;
      pV[it] = vbuf[(size_t)(b*T_+c)*D_ + h*64 + l];
    }
    if(tid<64){
      pI = invn_g[(size_t)(b*T_+tid)*H_ + h];
      pC = cum_g[(size_t)bh*N_*64 + tid];
    }
  }
  __syncthreads();

  for(int n=0;n<N_;++n){
    int t0 = n*C_;
    size_t base = ((size_t)bh*N_ + n)*4096;
    // W1: stage WCD + INV + CU
    #pragma unroll
    for(int j=0;j<4;++j){
      int idx4 = tid+256*j;
      *(float4*)(WCD + idx4*4) = pW[j];
    }
    if(tid<64){ INV[tid]=pI; CU[tid]=pC; }
    __syncthreads();
    // W2: stage RK (scaled), DW/DEc
    #pragma unroll
    for(int j=0;j<4;++j){
      int idx4 = tid+256*j;
      int c = idx4>>4;
      float iv = INV[c];
      float4 r = pR[j];
      r.x*=iv; r.y*=iv; r.z*=iv; r.w*=iv;
      *(float4*)(RK + idx4*4) = r;
    }
    if(tid<64){
      float last = CU[63];
      DW[tid]  = expf(last - CU[tid]);
      DEc[tid] = expf(CU[tid]);
    }
    __syncthreads();

    // consume pV into accumulators, then prefetch chunk n+1
    float vn[16];
    #pragma unroll
    for(int it=0;it<16;++it) vn[it]=pV[it];
    if(n+1 < N_){
      int t1 = t0 + C_;
      size_t base1 = base + 4096;
      #pragma unroll
      for(int j=0;j<4;++j){
        int idx4 = tid+256*j;
        pW[j] = *(const float4*)(wkop + base1 + (size_t)idx4*4);
        int c = idx4>>4, c4=(idx4&15)*4;
        pR[j] = *(const float4*)(x + (size_t)(b*T_+t1+c)*D_ + h*64 + c4);
      }
      #pragma unroll
      for(int it=0;it<16;++it){
        int c = 16*w+it;
        pV[it] = vbuf[(size_t)(b*T_+t1+c)*D_ + h*64 + l];
      }
      if(tid<64){
        pI = invn_g[(size_t)(b*T_+t1+tid)*H_ + h];
        pC = cum_g[((size_t)bh*N_+n+1)*64 + tid];
      }
    }

    // s_col = column l of S_pre
    float s_col[64];
    #pragma unroll
    for(int k=0;k<64;++k) s_col[k]=S[k*64+l];

    // v_new = v_corr - wkcd @ S_pre ; opart = exp(cum)*(rk @ S_pre)
    #pragma unroll 1
    for(int it=0;it<16;++it){
      int c = 16*w+it;
      float a = vn[it], o = 0.f;
      #pragma unroll
      for(int d4=0;d4<16;++d4){
        float4 wv = *(const float4*)&WCD[c*64+4*d4];
        float4 rv = *(const float4*)&RK [c*64+4*d4];
        a -= wv.x*s_col[4*d4]+wv.y*s_col[4*d4+1]+wv.z*s_col[4*d4+2]+wv.w*s_col[4*d4+3];
        o += rv.x*s_col[4*d4]+rv.y*s_col[4*d4+1]+rv.z*s_col[4*d4+2]+rv.w*s_col[4*d4+3];
      }
      vn[it]=a;
      vbuf[(size_t)(b*T_+t0+c)*D_ + h*64 + l] = a;
      wkop[base + c*64 + l] = DEc[c]*o;
    }
    __syncthreads();   // all reads of WCD done
    // VNS (= v_new * DW) over WCD
    #pragma unroll
    for(int it=0;it<16;++it){
      int c = 16*w+it;
      WCD[c*64+l] = vn[it]*DW[c];
    }
    __syncthreads();
    // S update: Snew[r][l] = elast*S[r][l] + sum_c wk[c][r]*VNS[c][l]
    float elast = expf(CU[63]);
    float vns_col[64];
    #pragma unroll
    for(int c=0;c<64;++c) vns_col[c]=WCD[c*64+l];
    float sn[16];
    #pragma unroll
    for(int it=0;it<16;++it){
      int r = 16*w+it;
      sn[it] = elast*S[r*64+l] + PREV[r]*vns_col[0];
    }
    #pragma unroll 1
    for(int c=1;c<64;++c){
      const float* rkrow = &RK[(c-1)*64 + 16*w];  // wk[c] = rk[c-1]
      float vc = vns_col[c];
      #pragma unroll
      for(int q=0;q<4;++q){
        float4 rseg = *(const float4*)(rkrow + 4*q);
        sn[4*q+0] += rseg.x*vc;
        sn[4*q+1] += rseg.y*vc;
        sn[4*q+2] += rseg.z*vc;
        sn[4*q+3] += rseg.w*vc;
      }
    }
    // Frobenius norm clip
    float p=0.f;
    #pragma unroll
    for(int it=0;it<16;++it) p += sn[it]*sn[it];
    p = wave_sum(p);
    if(l==0) P[w]=p;
    __syncthreads();
    float nrm = sqrtf(P[0]+P[1]+P[2]+P[3]);
    float scale = fminf(nrm,100.f)/fmaxf(nrm,1e-6f);
    #pragma unroll
    for(int it=0;it<16;++it){
      int r = 16*w+it;
      S[r*64+l] = sn[it]*scale;
    }
    if(tid<64) PREV[tid] = RK[63*64+tid];
    __syncthreads();
  }
}

// ---------------------------------------------------------------------------
// K5: o = gate*(opart + intra @ v_new); intra recomputed from rk/wk; o in-place
// ---------------------------------------------------------------------------
__global__ __launch_bounds__(256) void k_o(const float* __restrict__ x,
    const float* __restrict__ invn, const float* __restrict__ cum_g,
    const float* __restrict__ wkop, const float* __restrict__ gate_g,
    float* __restrict__ vbuf){
  int bid = blockIdx.x; int n = bid&63, h=(bid>>6)&15, b=bid>>10;
  int t0 = n*C_;
  __shared__ float sm[8256];
  float* RK = sm;        // 64x64 rk chunk, later INT (intra)
  float* VN = sm+4096;   // 64x64 v_new chunk
  float* CU = sm+8192;   // 64
  float* INT = RK;
  int tid=threadIdx.x, w=tid>>6, l=tid&63;
  if(tid<64) CU[tid] = cum_g[(size_t)bid*64 + tid];
  #pragma unroll 1
  for(int it=0;it<16;++it){
    int idx = tid+256*it; int c=idx>>6, dd=idx&63;
    size_t rr = (size_t)(b*T_+t0+c);
    RK[c*64+dd] = x[rr*D_ + h*64 + dd] * invn[rr*H_ + h];
    VN[idx]     = vbuf[rr*D_ + h*64 + dd];
  }
  __syncthreads();
  // wk column j=l into regs (wk[l] = rk[t0+l-1])
  float wkj[64];
  {
    int tw = t0+l-1;
    if(tw>=0){
      size_t r2 = (size_t)(b*T_+tw);
      float iv = invn[r2*H_ + h];
      #pragma unroll
      for(int d4=0; d4<16; ++d4){
        float4 u = *(const float4*)(x + r2*D_ + h*64 + 4*d4);
        wkj[4*d4+0]=u.x*iv; wkj[4*d4+1]=u.y*iv;
        wkj[4*d4+2]=u.z*iv; wkj[4*d4+3]=u.w*iv;
      }
    } else {
      #pragma unroll
      for(int dd=0;dd<64;++dd) wkj[dd]=0.f;
    }
  }
  // intra[i][l] = (rk_i . wk_l) * L[i][l]; write over RK (lockstep-safe per row)
  #pragma unroll 1
  for(int it=0;it<16;++it){
    int i = w + 4*it;
    float ar = 0.f;
    #pragma unroll
    for(int d4=0; d4<16; ++d4){
      float4 r4 = *(const float4*)&RK[i*64 + 4*d4];
      ar += r4.x*wkj[4*d4] + r4.y*wkj[4*d4+1] + r4.z*wkj[4*d4+2] + r4.w*wkj[4*d4+3];
    }
    float val = (l<=i) ? (ar*expf(CU[i]-CU[l])) : 0.f;
    INT[i*64+l] = val;   // all lanes' reads of row i complete before this (lockstep)
  }
  __syncthreads();
  float vn_col[64];
  #pragma unroll
  for(int k=0;k<64;++k) vn_col[k] = VN[k*64+l];
  #pragma unroll 1
  for(int it=0;it<16;++it){
    int c = w+4*it;
    float acc = 0.f;
    #pragma unroll
    for(int d4=0; d4<16; ++d4){
      float4 i4 = *(const float4*)&INT[c*64 + 4*d4];
      acc += i4.x*vn_col[4*d4] + i4.y*vn_col[4*d4+1] + i4.z*vn_col[4*d4+2] + i4.w*vn_col[4*d4+3];
    }
    size_t rr = (size_t)(b*T_+t0+c);
    float g  = gate_g[rr*H_ + h];
    float op = wkop[(size_t)bid*4096 + c*64 + l];
    vbuf[rr*D_ + h*64 + l] = (op + acc)*g;
  }
}

// ---------------------------------------------------------------------------
extern "C" void kernel_launch(void* const* d_in, const int* in_sizes, int n_in,
                              void* d_out, int out_size, void* d_ws, size_t ws_size,
                              hipStream_t stream) {
  const float* x       = (const float*)d_in[0];
  const float* w_write = (const float*)d_in[1];
  const float* w_gate  = (const float*)d_in[2];
  const float* w_out   = (const float*)d_in[3];
  const float* w_beta  = (const float*)d_in[4];
  const float* w_alpha = (const float*)d_in[5];
  const float* dt_bias = (const float*)d_in[6];
  const float* A_log   = (const float*)d_in[7];
  float* outp = (float*)d_out;

  const size_t big   = (size_t)BT_*D_;   // 16,777,216 floats
  const size_t small = (size_t)BT_*H_;   //    262,144 floats
  const size_t need  = (2*big + 5*small)*sizeof(float);   // ~139.5 MB
  if(ws_size < need) return;   // diagnostic: wrong-answer instead of fault

  float* ws   = (float*)d_ws;
  float* vbuf = ws;              // v -> v_corr -> v_new -> o
  float* wkop = vbuf + big;      // wk_cd -> opart
  float* invn = wkop + big;
  float* gate = invn + small;
  float* beta = gate + small;
  float* dec  = beta + small;
  float* cum  = dec  + small;

  k_small<<<dim3(BT_), dim3(256), 0, stream>>>(x, w_gate, w_beta, w_alpha,
      dt_bias, A_log, invn, gate, beta, dec);
  k_gemm_bb<<<dim3(D_/BN, BT_/BM), dim3(256), 0, stream>>>(x, w_write, vbuf,
      BT_, D_, D_);
  k_chunk<<<dim3(B_*H_*N_), dim3(256), 0, stream>>>(x, invn, beta, dec,
      cum, vbuf, wkop);
  k_scan<<<dim3(B_*H_), dim3(256), 0, stream>>>(x, invn, cum, vbuf, wkop);
  k_o<<<dim3(B_*H_*N_), dim3(256), 0, stream>>>(x, invn, cum, wkop, gate, vbuf);
  k_gemm_out<<<dim3(D_/BN, BT_/BM), dim3(256), 0, stream>>>(vbuf, w_out, x,
      outp, BT_, D_, D_);
}